// Round 1
// baseline (361.354 us; speedup 1.0000x reference)
//
#include <hip/hip_runtime.h>

#define B_   256
#define T_   256
#define DENC 512
#define H_   512
#define NC   96

typedef __bf16 bf16_t;
typedef bf16_t bf16x8 __attribute__((ext_vector_type(8)));
typedef unsigned short ushort8_t __attribute__((ext_vector_type(8)));
typedef float f32x4 __attribute__((ext_vector_type(4)));

__device__ __forceinline__ unsigned short f2bf(float f) {
    union { float f; unsigned int u; } v; v.f = f;
    unsigned int r = v.u + 0x7FFFu + ((v.u >> 16) & 1u);
    return (unsigned short)(r >> 16);
}
__device__ __forceinline__ float fast_tanh(float x) {
    float e2 = __expf(2.f * x);
    return 1.f - 2.f / (e2 + 1.f);
}
__device__ __forceinline__ float fast_sig(float x) {
    return 1.f / (1.f + __expf(-x));
}

// ---------------- K0: Wt[h][d] = bf16(Wi2h[d][h]) ----------------
__global__ void k0_wt(const float* __restrict__ Wi2h, unsigned short* __restrict__ Wt) {
    __shared__ float tile[32][33];
    int tx = threadIdx.x, ty = threadIdx.y;
    int bx = blockIdx.x, by = blockIdx.y;
#pragma unroll
    for (int j = 0; j < 4; ++j) {
        int r = by * 32 + ty + j * 8;
        int c = bx * 32 + tx;
        tile[ty + j * 8][tx] = Wi2h[r * 512 + c];
    }
    __syncthreads();
#pragma unroll
    for (int j = 0; j < 4; ++j) {
        int h = bx * 32 + ty + j * 8;
        int d = by * 32 + tx;
        Wt[h * 512 + d] = f2bf(tile[tx][ty + j * 8]);
    }
}

// ---------------- K1: h_proj = prev_h @ Wh2h + bh2h ----------------
__global__ void k1_hproj(const float* __restrict__ prev_h, const float* __restrict__ Wh2h,
                         const float* __restrict__ bh2h, float* __restrict__ h_proj) {
    __shared__ float sh[512];
    int b = blockIdx.x, tid = threadIdx.x;
    sh[tid]       = prev_h[b * 512 + tid];
    sh[tid + 256] = prev_h[b * 512 + tid + 256];
    __syncthreads();
    float a0 = 0.f, a1 = 0.f;
#pragma unroll 4
    for (int k = 0; k < 512; ++k) {
        float h = sh[k];
        a0 += h * Wh2h[k * 512 + tid];
        a1 += h * Wh2h[k * 512 + tid + 256];
    }
    h_proj[b * 512 + tid]       = a0 + bh2h[tid];
    h_proj[b * 512 + tid + 256] = a1 + bh2h[tid + 256];
}

// ---------------- K2: fused e = tanh(bH@Wi2h + h_proj) @ Wscore ----------------
// M = B*T rows (64/block), N = 512 (wave w owns cols [w*128, w*128+128)), K = 512.
__launch_bounds__(256, 2)
__global__ void k2_scores(const float* __restrict__ batch_H,
                          const unsigned short* __restrict__ Wt,   // [512 h][512 d] bf16
                          const float* __restrict__ h_proj,
                          const float* __restrict__ Wscore,
                          float* __restrict__ e_out) {
    __shared__ __align__(16) unsigned short Alds[64 * 264];  // 64 rows x 256 k, pad->264
    __shared__ float hp[512];
    __shared__ float wsc[512];
    __shared__ float e_red[256];

    int tid = threadIdx.x;
    int m0  = blockIdx.x * 64;
    int b   = m0 >> 8;

    hp[tid]        = h_proj[b * 512 + tid];
    hp[tid + 256]  = h_proj[b * 512 + tid + 256];
    wsc[tid]       = Wscore[tid];
    wsc[tid + 256] = Wscore[tid + 256];

    int wave = tid >> 6;
    int lane = tid & 63;
    int l15  = lane & 15;
    int g    = lane >> 4;

    f32x4 acc[4][8];
#pragma unroll
    for (int mf = 0; mf < 4; ++mf)
#pragma unroll
        for (int nf = 0; nf < 8; ++nf)
            acc[mf][nf] = (f32x4){0.f, 0.f, 0.f, 0.f};

    for (int ks = 0; ks < 2; ++ks) {
        if (ks) __syncthreads();
        // stage 64 x 256 fp32 -> bf16 LDS
        for (int i = tid; i < 2048; i += 256) {
            int row = i >> 5;
            int c8  = (i & 31) << 3;
            const float* src = batch_H + (size_t)(m0 + row) * 512 + ks * 256 + c8;
            float4 f0 = *(const float4*)(src);
            float4 f1 = *(const float4*)(src + 4);
            ushort8_t u;
            u[0] = f2bf(f0.x); u[1] = f2bf(f0.y); u[2] = f2bf(f0.z); u[3] = f2bf(f0.w);
            u[4] = f2bf(f1.x); u[5] = f2bf(f1.y); u[6] = f2bf(f1.z); u[7] = f2bf(f1.w);
            *(ushort8_t*)(&Alds[row * 264 + c8]) = u;
        }
        __syncthreads();

#pragma unroll
        for (int kb = 0; kb < 8; ++kb) {
            int kglob = ks * 256 + kb * 32 + g * 8;
            bf16x8 bfrag[8];
#pragma unroll
            for (int nf = 0; nf < 8; ++nf) {
                int n = wave * 128 + nf * 16 + l15;
                ushort8_t u = *(const ushort8_t*)(Wt + (size_t)n * 512 + kglob);
                bfrag[nf] = __builtin_bit_cast(bf16x8, u);
            }
            bf16x8 afrag[4];
#pragma unroll
            for (int mf = 0; mf < 4; ++mf) {
                ushort8_t u = *(const ushort8_t*)(&Alds[(mf * 16 + l15) * 264 + kb * 32 + g * 8]);
                afrag[mf] = __builtin_bit_cast(bf16x8, u);
            }
#pragma unroll
            for (int nf = 0; nf < 8; ++nf)
#pragma unroll
                for (int mf = 0; mf < 4; ++mf)
                    acc[mf][nf] = __builtin_amdgcn_mfma_f32_16x16x32_bf16(
                        afrag[mf], bfrag[nf], acc[mf][nf], 0, 0, 0);
        }
    }

    // epilogue: e_partial(lane) = sum_n wsc[n] * tanh(acc + hp[n])
    float s[4][4];
#pragma unroll
    for (int mf = 0; mf < 4; ++mf)
#pragma unroll
        for (int r = 0; r < 4; ++r) s[mf][r] = 0.f;

#pragma unroll
    for (int nf = 0; nf < 8; ++nf) {
        int n = wave * 128 + nf * 16 + l15;
        float hpv = hp[n], wv = wsc[n];
#pragma unroll
        for (int mf = 0; mf < 4; ++mf)
#pragma unroll
            for (int r = 0; r < 4; ++r)
                s[mf][r] += wv * fast_tanh(acc[mf][nf][r] + hpv);
    }
    // reduce across the 16 lanes that share (g, r) -> n direction
#pragma unroll
    for (int mf = 0; mf < 4; ++mf)
#pragma unroll
        for (int r = 0; r < 4; ++r) {
            float v = s[mf][r];
            v += __shfl_xor(v, 1);
            v += __shfl_xor(v, 2);
            v += __shfl_xor(v, 4);
            v += __shfl_xor(v, 8);
            s[mf][r] = v;
        }
    if (l15 == 0) {
#pragma unroll
        for (int mf = 0; mf < 4; ++mf)
#pragma unroll
            for (int r = 0; r < 4; ++r)
                e_red[wave * 64 + mf * 16 + g * 4 + r] = s[mf][r];
    }
    __syncthreads();
    if (tid < 64) {
        float v = e_red[tid] + e_red[64 + tid] + e_red[128 + tid] + e_red[192 + tid];
        e_out[m0 + tid] = v;
    }
}

// ---------------- K3: softmax over T per b ----------------
__global__ void k3_softmax(const float* __restrict__ e, float* __restrict__ alpha_out) {
    __shared__ float red[4];
    int b = blockIdx.x, tid = threadIdx.x;
    float v = e[b * 256 + tid];
    float m = v;
#pragma unroll
    for (int off = 32; off; off >>= 1) m = fmaxf(m, __shfl_xor(m, off));
    if ((tid & 63) == 0) red[tid >> 6] = m;
    __syncthreads();
    m = fmaxf(fmaxf(red[0], red[1]), fmaxf(red[2], red[3]));
    float p = __expf(v - m);
    __syncthreads();
    float sum = p;
#pragma unroll
    for (int off = 32; off; off >>= 1) sum += __shfl_xor(sum, off);
    if ((tid & 63) == 0) red[tid >> 6] = sum;
    __syncthreads();
    sum = red[0] + red[1] + red[2] + red[3];
    alpha_out[b * 256 + tid] = p / sum;
}

// ---------------- K4: context[b,d] = sum_t alpha[b,t] * batch_H[b,t,d] ----------------
__global__ void k4_context(const float* __restrict__ batch_H, const float* __restrict__ alpha,
                           float* __restrict__ context) {
    __shared__ float al[256];
    int b = blockIdx.y, dc = blockIdx.x, tid = threadIdx.x;
    al[tid] = alpha[b * 256 + tid];
    __syncthreads();
    int d = dc * 256 + tid;
    const float* bh = batch_H + (size_t)b * 256 * 512 + d;
    float acc = 0.f;
#pragma unroll 4
    for (int t = 0; t < 256; ++t)
        acc += al[t] * bh[(size_t)t * 512];
    context[b * 512 + d] = acc;
}

// ---------------- K5: z = [context;onehot;prev_h] @ [Wk;Uk] (no bias) ----------------
__global__ void k5_zgemm(const float* __restrict__ context, const float* __restrict__ onehots,
                         const float* __restrict__ prev_h, const float* __restrict__ Wk,
                         const float* __restrict__ Uk, float* __restrict__ z) {
    __shared__ float As[32 * 33];
    __shared__ __align__(16) float Bs[32 * 132];
    int tid = threadIdx.x;
    int j0 = blockIdx.x * 128;
    int b0 = blockIdx.y * 32;
    int ty = tid >> 5, tx = tid & 31;
    float acc[4][4] = {{0.f}};

    for (int k0 = 0; k0 < 1120; k0 += 32) {
        for (int i = tid; i < 32 * 32; i += 256) {
            int r = i >> 5, kk = i & 31;
            int gk = k0 + kk, gb = b0 + r;
            float v;
            if (gk < 512)      v = context[gb * 512 + gk];
            else if (gk < 608) v = onehots[gb * 96 + gk - 512];
            else               v = prev_h[gb * 512 + gk - 608];
            As[r * 33 + kk] = v;
        }
        for (int i = tid; i < 32 * 128; i += 256) {
            int kk = i >> 7, jj = i & 127;
            int gk = k0 + kk;
            float v = (gk < 608) ? Wk[(size_t)gk * 2048 + j0 + jj]
                                 : Uk[(size_t)(gk - 608) * 2048 + j0 + jj];
            Bs[kk * 132 + jj] = v;
        }
        __syncthreads();
#pragma unroll 8
        for (int kk = 0; kk < 32; ++kk) {
            float a0 = As[(ty * 4 + 0) * 33 + kk];
            float a1 = As[(ty * 4 + 1) * 33 + kk];
            float a2 = As[(ty * 4 + 2) * 33 + kk];
            float a3 = As[(ty * 4 + 3) * 33 + kk];
            float4 bb = *(const float4*)(&Bs[kk * 132 + tx * 4]);
            acc[0][0] += a0 * bb.x; acc[0][1] += a0 * bb.y; acc[0][2] += a0 * bb.z; acc[0][3] += a0 * bb.w;
            acc[1][0] += a1 * bb.x; acc[1][1] += a1 * bb.y; acc[1][2] += a1 * bb.z; acc[1][3] += a1 * bb.w;
            acc[2][0] += a2 * bb.x; acc[2][1] += a2 * bb.y; acc[2][2] += a2 * bb.z; acc[2][3] += a2 * bb.w;
            acc[3][0] += a3 * bb.x; acc[3][1] += a3 * bb.y; acc[3][2] += a3 * bb.z; acc[3][3] += a3 * bb.w;
        }
        __syncthreads();
    }
#pragma unroll
    for (int r = 0; r < 4; ++r)
#pragma unroll
        for (int c = 0; c < 4; ++c)
            z[(size_t)(b0 + ty * 4 + r) * 2048 + j0 + tx * 4 + c] = acc[r][c];
}

// ---------------- K6: gates ----------------
__global__ void k6_gates(const float* __restrict__ z, const float* __restrict__ bk,
                         const float* __restrict__ prev_c, float* __restrict__ out) {
    int idx = blockIdx.x * 256 + threadIdx.x;   // 0 .. 131071
    int b = idx >> 9, h = idx & 511;
    const float* zb = z + (size_t)b * 2048;
    float zi = zb[h]        + bk[h];
    float zf = zb[512 + h]  + bk[512 + h];
    float zg = zb[1024 + h] + bk[1024 + h];
    float zo = zb[1536 + h] + bk[1536 + h];
    float c  = fast_sig(zf) * prev_c[idx] + fast_sig(zi) * fast_tanh(zg);
    float hn = fast_sig(zo) * fast_tanh(c);
    out[idx]          = hn;   // h_new
    out[131072 + idx] = c;    // c_new
}

extern "C" void kernel_launch(void* const* d_in, const int* in_sizes, int n_in,
                              void* d_out, int out_size, void* d_ws, size_t ws_size,
                              hipStream_t stream) {
    (void)in_sizes; (void)n_in; (void)out_size; (void)ws_size;
    const float* prev_h  = (const float*)d_in[0];
    const float* prev_c  = (const float*)d_in[1];
    const float* batch_H = (const float*)d_in[2];
    const float* onehots = (const float*)d_in[3];
    const float* Wi2h    = (const float*)d_in[4];
    const float* Wh2h    = (const float*)d_in[5];
    const float* bh2h    = (const float*)d_in[6];
    const float* Wscore  = (const float*)d_in[7];
    const float* Wk      = (const float*)d_in[8];
    const float* Uk      = (const float*)d_in[9];
    const float* bk      = (const float*)d_in[10];
    float* out = (float*)d_out;

    char* ws = (char*)d_ws;
    float* h_proj        = (float*)(ws + 0);        // 256*512*4   = 524288
    float* e             = (float*)(ws + 524288);   // 65536*4     = 262144
    float* context       = (float*)(ws + 786432);   // 256*512*4   = 524288
    float* z             = (float*)(ws + 1310720);  // 256*2048*4  = 2097152
    unsigned short* Wt   = (unsigned short*)(ws + 3407872); // 512*512*2 = 524288

    float* alpha = out + 262144;   // [B,T,1] output region, also consumed by k4

    k0_wt    <<<dim3(16, 16), dim3(32, 8), 0, stream>>>(Wi2h, Wt);
    k1_hproj <<<256, 256, 0, stream>>>(prev_h, Wh2h, bh2h, h_proj);
    k2_scores<<<1024, 256, 0, stream>>>(batch_H, Wt, h_proj, Wscore, e);
    k3_softmax<<<256, 256, 0, stream>>>(e, alpha);
    k4_context<<<dim3(2, 256), 256, 0, stream>>>(batch_H, alpha, context);
    k5_zgemm <<<dim3(16, 8), 256, 0, stream>>>(context, onehots, prev_h, Wk, Uk, z);
    k6_gates <<<512, 256, 0, stream>>>(z, bk, prev_c, out);
}

// Round 2
// 200.110 us; speedup vs baseline: 1.8058x; 1.8058x over previous
//
#include <hip/hip_runtime.h>

#define B_   256
#define T_   256
#define DENC 512
#define H_   512
#define NC   96

typedef __bf16 bf16_t;
typedef bf16_t bf16x8 __attribute__((ext_vector_type(8)));
typedef unsigned short ushort8_t __attribute__((ext_vector_type(8)));
typedef float f32x4 __attribute__((ext_vector_type(4)));

__device__ __forceinline__ unsigned short f2bf(float f) {
    union { float f; unsigned int u; } v; v.f = f;
    unsigned int r = v.u + 0x7FFFu + ((v.u >> 16) & 1u);
    return (unsigned short)(r >> 16);
}
__device__ __forceinline__ float fast_tanh(float x) {
    float e2 = __expf(2.f * x);
    return 1.f - 2.f / (e2 + 1.f);
}
__device__ __forceinline__ float fast_sig(float x) {
    return 1.f / (1.f + __expf(-x));
}

// ---------------- K0: Wt[h][d] = bf16(Wi2h[d][h]) ----------------
__global__ void k0_wt(const float* __restrict__ Wi2h, unsigned short* __restrict__ Wt) {
    __shared__ float tile[32][33];
    int tx = threadIdx.x, ty = threadIdx.y;
    int bx = blockIdx.x, by = blockIdx.y;
#pragma unroll
    for (int j = 0; j < 4; ++j) {
        int r = by * 32 + ty + j * 8;
        int c = bx * 32 + tx;
        tile[ty + j * 8][tx] = Wi2h[r * 512 + c];
    }
    __syncthreads();
#pragma unroll
    for (int j = 0; j < 4; ++j) {
        int h = bx * 32 + ty + j * 8;
        int d = by * 32 + tx;
        Wt[h * 512 + d] = f2bf(tile[tx][ty + j * 8]);
    }
}

// ---------------- K1: h_proj = prev_h @ Wh2h + bh2h ----------------
__global__ void k1_hproj(const float* __restrict__ prev_h, const float* __restrict__ Wh2h,
                         const float* __restrict__ bh2h, float* __restrict__ h_proj) {
    __shared__ float sh[512];
    int b = blockIdx.x, tid = threadIdx.x;
    sh[tid]       = prev_h[b * 512 + tid];
    sh[tid + 256] = prev_h[b * 512 + tid + 256];
    __syncthreads();
    float a0 = 0.f, a1 = 0.f;
#pragma unroll 4
    for (int k = 0; k < 512; ++k) {
        float h = sh[k];
        a0 += h * Wh2h[k * 512 + tid];
        a1 += h * Wh2h[k * 512 + tid + 256];
    }
    h_proj[b * 512 + tid]       = a0 + bh2h[tid];
    h_proj[b * 512 + tid + 256] = a1 + bh2h[tid + 256];
}

// ---------------- K2: fused e = tanh(bH@Wi2h + h_proj) @ Wscore ----------------
__launch_bounds__(256, 2)
__global__ void k2_scores(const float* __restrict__ batch_H,
                          const unsigned short* __restrict__ Wt,   // [512 h][512 d] bf16
                          const float* __restrict__ h_proj,
                          const float* __restrict__ Wscore,
                          float* __restrict__ e_out) {
    __shared__ __align__(16) unsigned short Alds[64 * 264];
    __shared__ float hp[512];
    __shared__ float wsc[512];
    __shared__ float e_red[256];

    int tid = threadIdx.x;
    int m0  = blockIdx.x * 64;
    int b   = m0 >> 8;

    hp[tid]        = h_proj[b * 512 + tid];
    hp[tid + 256]  = h_proj[b * 512 + tid + 256];
    wsc[tid]       = Wscore[tid];
    wsc[tid + 256] = Wscore[tid + 256];

    int wave = tid >> 6;
    int lane = tid & 63;
    int l15  = lane & 15;
    int g    = lane >> 4;

    f32x4 acc[4][8];
#pragma unroll
    for (int mf = 0; mf < 4; ++mf)
#pragma unroll
        for (int nf = 0; nf < 8; ++nf)
            acc[mf][nf] = (f32x4){0.f, 0.f, 0.f, 0.f};

    for (int ks = 0; ks < 2; ++ks) {
        if (ks) __syncthreads();
        for (int i = tid; i < 2048; i += 256) {
            int row = i >> 5;
            int c8  = (i & 31) << 3;
            const float* src = batch_H + (size_t)(m0 + row) * 512 + ks * 256 + c8;
            float4 f0 = *(const float4*)(src);
            float4 f1 = *(const float4*)(src + 4);
            ushort8_t u;
            u[0] = f2bf(f0.x); u[1] = f2bf(f0.y); u[2] = f2bf(f0.z); u[3] = f2bf(f0.w);
            u[4] = f2bf(f1.x); u[5] = f2bf(f1.y); u[6] = f2bf(f1.z); u[7] = f2bf(f1.w);
            *(ushort8_t*)(&Alds[row * 264 + c8]) = u;
        }
        __syncthreads();

#pragma unroll
        for (int kb = 0; kb < 8; ++kb) {
            int kglob = ks * 256 + kb * 32 + g * 8;
            bf16x8 bfrag[8];
#pragma unroll
            for (int nf = 0; nf < 8; ++nf) {
                int n = wave * 128 + nf * 16 + l15;
                ushort8_t u = *(const ushort8_t*)(Wt + (size_t)n * 512 + kglob);
                bfrag[nf] = __builtin_bit_cast(bf16x8, u);
            }
            bf16x8 afrag[4];
#pragma unroll
            for (int mf = 0; mf < 4; ++mf) {
                ushort8_t u = *(const ushort8_t*)(&Alds[(mf * 16 + l15) * 264 + kb * 32 + g * 8]);
                afrag[mf] = __builtin_bit_cast(bf16x8, u);
            }
#pragma unroll
            for (int nf = 0; nf < 8; ++nf)
#pragma unroll
                for (int mf = 0; mf < 4; ++mf)
                    acc[mf][nf] = __builtin_amdgcn_mfma_f32_16x16x32_bf16(
                        afrag[mf], bfrag[nf], acc[mf][nf], 0, 0, 0);
        }
    }

    float s[4][4];
#pragma unroll
    for (int mf = 0; mf < 4; ++mf)
#pragma unroll
        for (int r = 0; r < 4; ++r) s[mf][r] = 0.f;

#pragma unroll
    for (int nf = 0; nf < 8; ++nf) {
        int n = wave * 128 + nf * 16 + l15;
        float hpv = hp[n], wv = wsc[n];
#pragma unroll
        for (int mf = 0; mf < 4; ++mf)
#pragma unroll
            for (int r = 0; r < 4; ++r)
                s[mf][r] += wv * fast_tanh(acc[mf][nf][r] + hpv);
    }
#pragma unroll
    for (int mf = 0; mf < 4; ++mf)
#pragma unroll
        for (int r = 0; r < 4; ++r) {
            float v = s[mf][r];
            v += __shfl_xor(v, 1);
            v += __shfl_xor(v, 2);
            v += __shfl_xor(v, 4);
            v += __shfl_xor(v, 8);
            s[mf][r] = v;
        }
    if (l15 == 0) {
#pragma unroll
        for (int mf = 0; mf < 4; ++mf)
#pragma unroll
            for (int r = 0; r < 4; ++r)
                e_red[wave * 64 + mf * 16 + g * 4 + r] = s[mf][r];
    }
    __syncthreads();
    if (tid < 64) {
        float v = e_red[tid] + e_red[64 + tid] + e_red[128 + tid] + e_red[192 + tid];
        e_out[m0 + tid] = v;
    }
}

// ---------------- K3: softmax over T per b ----------------
__global__ void k3_softmax(const float* __restrict__ e, float* __restrict__ alpha_out) {
    __shared__ float red[4];
    int b = blockIdx.x, tid = threadIdx.x;
    float v = e[b * 256 + tid];
    float m = v;
#pragma unroll
    for (int off = 32; off; off >>= 1) m = fmaxf(m, __shfl_xor(m, off));
    if ((tid & 63) == 0) red[tid >> 6] = m;
    __syncthreads();
    m = fmaxf(fmaxf(red[0], red[1]), fmaxf(red[2], red[3]));
    float p = __expf(v - m);
    __syncthreads();
    float sum = p;
#pragma unroll
    for (int off = 32; off; off >>= 1) sum += __shfl_xor(sum, off);
    if ((tid & 63) == 0) red[tid >> 6] = sum;
    __syncthreads();
    sum = red[0] + red[1] + red[2] + red[3];
    alpha_out[b * 256 + tid] = p / sum;
}

// ---------------- K4: context[b,d] = sum_t alpha[b,t] * batch_H[b,t,d] ----------------
__global__ void k4_context(const float* __restrict__ batch_H, const float* __restrict__ alpha,
                           float* __restrict__ context) {
    __shared__ float al[256];
    int b = blockIdx.y, dc = blockIdx.x, tid = threadIdx.x;
    al[tid] = alpha[b * 256 + tid];
    __syncthreads();
    int d = dc * 256 + tid;
    const float* bh = batch_H + (size_t)b * 256 * 512 + d;
    float acc = 0.f;
#pragma unroll 4
    for (int t = 0; t < 256; ++t)
        acc += al[t] * bh[(size_t)t * 512];
    context[b * 512 + d] = acc;
}

// ---------------- K5t: Wzt[n][k] = bf16([Wk;Uk][k][n]), n<2048, k<1120 ----------------
__global__ void k5t_wzt(const float* __restrict__ Wk, const float* __restrict__ Uk,
                        unsigned short* __restrict__ Wzt) {
    __shared__ float tile[32][33];
    int tx = threadIdx.x, ty = threadIdx.y;
    int bx = blockIdx.x;   // k-tile, 0..34
    int by = blockIdx.y;   // n-tile, 0..63
#pragma unroll
    for (int j = 0; j < 4; ++j) {
        int k = bx * 32 + ty + j * 8;
        int c = by * 32 + tx;
        float v = (k < 608) ? Wk[(size_t)k * 2048 + c] : Uk[(size_t)(k - 608) * 2048 + c];
        tile[ty + j * 8][tx] = v;
    }
    __syncthreads();
#pragma unroll
    for (int j = 0; j < 4; ++j) {
        int n = by * 32 + ty + j * 8;
        int k = bx * 32 + tx;
        Wzt[(size_t)n * 1120 + k] = f2bf(tile[tx][ty + j * 8]);
    }
}

// ---------------- K5x: xb[b][k] = bf16([context;onehots;prev_h]) ----------------
__global__ void k5x_build(const float* __restrict__ context, const float* __restrict__ onehots,
                          const float* __restrict__ prev_h, unsigned short* __restrict__ xb) {
    int b = blockIdx.x, tid = threadIdx.x;
    for (int k = tid; k < 1120; k += 256) {
        float v;
        if (k < 512)      v = context[b * 512 + k];
        else if (k < 608) v = onehots[b * 96 + k - 512];
        else              v = prev_h[b * 512 + k - 608];
        xb[b * 1120 + k] = f2bf(v);
    }
}

// ---------------- K5m: fused z-GEMM + LSTM gates ----------------
// Tile: 32 rows (b) x 64 h-cols, each wave owns 16 h-cols x all 4 gates.
__launch_bounds__(256)
__global__ void k5m_fused(const unsigned short* __restrict__ xb,   // [256][1120] bf16
                          const unsigned short* __restrict__ Wzt,  // [2048][1120] bf16
                          const float* __restrict__ bk,
                          const float* __restrict__ prev_c,
                          float* __restrict__ out) {
    __shared__ __align__(16) unsigned short Axs[32 * 232];  // 32 rows x 224 k, pad->232

    int tid  = threadIdx.x;
    int wave = tid >> 6;
    int lane = tid & 63;
    int l15  = lane & 15;
    int g    = lane >> 4;
    int b0   = blockIdx.y * 32;
    int h0   = blockIdx.x * 64 + wave * 16;

    f32x4 acc[2][4];
#pragma unroll
    for (int mf = 0; mf < 2; ++mf)
#pragma unroll
        for (int gt = 0; gt < 4; ++gt)
            acc[mf][gt] = (f32x4){0.f, 0.f, 0.f, 0.f};

    const unsigned short* wbase = Wzt + (size_t)(h0 + l15) * 1120;

    for (int ks = 0; ks < 5; ++ks) {
        if (ks) __syncthreads();
        int kbase = ks * 224;
        for (int i = tid; i < 896; i += 256) {
            int row = i / 28;
            int c8  = (i % 28) * 8;
            *(ushort8_t*)(&Axs[row * 232 + c8]) =
                *(const ushort8_t*)(&xb[(size_t)(b0 + row) * 1120 + kbase + c8]);
        }
        __syncthreads();

        // register double-buffer for B fragments
        bf16x8 bcur[4], bnxt[4];
#pragma unroll
        for (int gt = 0; gt < 4; ++gt)
            bcur[gt] = __builtin_bit_cast(bf16x8,
                *(const ushort8_t*)(wbase + (size_t)gt * 512 * 1120 + kbase + g * 8));

#pragma unroll
        for (int kb = 0; kb < 7; ++kb) {
            if (kb < 6) {
                int kg = kbase + (kb + 1) * 32 + g * 8;
#pragma unroll
                for (int gt = 0; gt < 4; ++gt)
                    bnxt[gt] = __builtin_bit_cast(bf16x8,
                        *(const ushort8_t*)(wbase + (size_t)gt * 512 * 1120 + kg));
            }
            bf16x8 afrag[2];
#pragma unroll
            for (int mf = 0; mf < 2; ++mf)
                afrag[mf] = __builtin_bit_cast(bf16x8,
                    *(const ushort8_t*)(&Axs[(mf * 16 + l15) * 232 + kb * 32 + g * 8]));
#pragma unroll
            for (int gt = 0; gt < 4; ++gt)
#pragma unroll
                for (int mf = 0; mf < 2; ++mf)
                    acc[mf][gt] = __builtin_amdgcn_mfma_f32_16x16x32_bf16(
                        afrag[mf], bcur[gt], acc[mf][gt], 0, 0, 0);
#pragma unroll
            for (int gt = 0; gt < 4; ++gt) bcur[gt] = bnxt[gt];
        }
    }

    // epilogue: gates fused, C-layout col=l15, row=g*4+r (+mf*16)
    int h = h0 + l15;
    float bi = bk[h], bfv = bk[512 + h], bg = bk[1024 + h], bo = bk[1536 + h];
#pragma unroll
    for (int mf = 0; mf < 2; ++mf)
#pragma unroll
        for (int r = 0; r < 4; ++r) {
            int m = b0 + mf * 16 + g * 4 + r;
            float zi = acc[mf][0][r] + bi;
            float zf = acc[mf][1][r] + bfv;
            float zg = acc[mf][2][r] + bg;
            float zo = acc[mf][3][r] + bo;
            float c  = fast_sig(zf) * prev_c[m * 512 + h] + fast_sig(zi) * fast_tanh(zg);
            float hn = fast_sig(zo) * fast_tanh(c);
            out[m * 512 + h]          = hn;
            out[131072 + m * 512 + h] = c;
        }
}

// ---------------- Fallback path (round-1 proven): k5 scalar GEMM + k6 ----------------
__global__ void k5_zgemm(const float* __restrict__ context, const float* __restrict__ onehots,
                         const float* __restrict__ prev_h, const float* __restrict__ Wk,
                         const float* __restrict__ Uk, float* __restrict__ z) {
    __shared__ float As[32 * 33];
    __shared__ __align__(16) float Bs[32 * 132];
    int tid = threadIdx.x;
    int j0 = blockIdx.x * 128;
    int b0 = blockIdx.y * 32;
    int ty = tid >> 5, tx = tid & 31;
    float acc[4][4] = {{0.f}};

    for (int k0 = 0; k0 < 1120; k0 += 32) {
        for (int i = tid; i < 32 * 32; i += 256) {
            int r = i >> 5, kk = i & 31;
            int gk = k0 + kk, gb = b0 + r;
            float v;
            if (gk < 512)      v = context[gb * 512 + gk];
            else if (gk < 608) v = onehots[gb * 96 + gk - 512];
            else               v = prev_h[gb * 512 + gk - 608];
            As[r * 33 + kk] = v;
        }
        for (int i = tid; i < 32 * 128; i += 256) {
            int kk = i >> 7, jj = i & 127;
            int gk = k0 + kk;
            float v = (gk < 608) ? Wk[(size_t)gk * 2048 + j0 + jj]
                                 : Uk[(size_t)(gk - 608) * 2048 + j0 + jj];
            Bs[kk * 132 + jj] = v;
        }
        __syncthreads();
#pragma unroll 8
        for (int kk = 0; kk < 32; ++kk) {
            float a0 = As[(ty * 4 + 0) * 33 + kk];
            float a1 = As[(ty * 4 + 1) * 33 + kk];
            float a2 = As[(ty * 4 + 2) * 33 + kk];
            float a3 = As[(ty * 4 + 3) * 33 + kk];
            float4 bb = *(const float4*)(&Bs[kk * 132 + tx * 4]);
            acc[0][0] += a0 * bb.x; acc[0][1] += a0 * bb.y; acc[0][2] += a0 * bb.z; acc[0][3] += a0 * bb.w;
            acc[1][0] += a1 * bb.x; acc[1][1] += a1 * bb.y; acc[1][2] += a1 * bb.z; acc[1][3] += a1 * bb.w;
            acc[2][0] += a2 * bb.x; acc[2][1] += a2 * bb.y; acc[2][2] += a2 * bb.z; acc[2][3] += a2 * bb.w;
            acc[3][0] += a3 * bb.x; acc[3][1] += a3 * bb.y; acc[3][2] += a3 * bb.z; acc[3][3] += a3 * bb.w;
        }
        __syncthreads();
    }
#pragma unroll
    for (int r = 0; r < 4; ++r)
#pragma unroll
        for (int c = 0; c < 4; ++c)
            z[(size_t)(b0 + ty * 4 + r) * 2048 + j0 + tx * 4 + c] = acc[r][c];
}

__global__ void k6_gates(const float* __restrict__ z, const float* __restrict__ bk,
                         const float* __restrict__ prev_c, float* __restrict__ out) {
    int idx = blockIdx.x * 256 + threadIdx.x;
    int b = idx >> 9, h = idx & 511;
    const float* zb = z + (size_t)b * 2048;
    float zi = zb[h]        + bk[h];
    float zf = zb[512 + h]  + bk[512 + h];
    float zg = zb[1024 + h] + bk[1024 + h];
    float zo = zb[1536 + h] + bk[1536 + h];
    float c  = fast_sig(zf) * prev_c[idx] + fast_sig(zi) * fast_tanh(zg);
    float hn = fast_sig(zo) * fast_tanh(c);
    out[idx]          = hn;
    out[131072 + idx] = c;
}

extern "C" void kernel_launch(void* const* d_in, const int* in_sizes, int n_in,
                              void* d_out, int out_size, void* d_ws, size_t ws_size,
                              hipStream_t stream) {
    (void)in_sizes; (void)n_in; (void)out_size;
    const float* prev_h  = (const float*)d_in[0];
    const float* prev_c  = (const float*)d_in[1];
    const float* batch_H = (const float*)d_in[2];
    const float* onehots = (const float*)d_in[3];
    const float* Wi2h    = (const float*)d_in[4];
    const float* Wh2h    = (const float*)d_in[5];
    const float* bh2h    = (const float*)d_in[6];
    const float* Wscore  = (const float*)d_in[7];
    const float* Wk      = (const float*)d_in[8];
    const float* Uk      = (const float*)d_in[9];
    const float* bk      = (const float*)d_in[10];
    float* out = (float*)d_out;
    float* alpha = out + 262144;

    char* ws = (char*)d_ws;

    if (ws_size >= 5898240) {
        // New layout: [0,768K): h_proj(512K)+e(256K), later reused as xb(573K)
        //             [768K, 1280K): context
        //             [1280K, 5.9M): Wzt (4.59M), start aliased as Wt(512K) for k0/k2
        float* h_proj      = (float*)(ws + 0);
        float* e           = (float*)(ws + 524288);
        float* context     = (float*)(ws + 786432);
        unsigned short* Wzt = (unsigned short*)(ws + 1310720);
        unsigned short* Wt  = (unsigned short*)(ws + 1310720);  // alias, dead before k5t writes
        unsigned short* xb  = (unsigned short*)(ws + 0);        // alias over h_proj+e, dead after k3

        k0_wt    <<<dim3(16, 16), dim3(32, 8), 0, stream>>>(Wi2h, Wt);
        k1_hproj <<<256, 256, 0, stream>>>(prev_h, Wh2h, bh2h, h_proj);
        k2_scores<<<1024, 256, 0, stream>>>(batch_H, Wt, h_proj, Wscore, e);
        k3_softmax<<<256, 256, 0, stream>>>(e, alpha);
        k4_context<<<dim3(2, 256), 256, 0, stream>>>(batch_H, alpha, context);
        k5t_wzt  <<<dim3(35, 64), dim3(32, 8), 0, stream>>>(Wk, Uk, Wzt);
        k5x_build<<<256, 256, 0, stream>>>(context, onehots, prev_h, xb);
        k5m_fused<<<dim3(8, 8), 256, 0, stream>>>(xb, Wzt, bk, prev_c, out);
    } else {
        // Fallback: round-1 proven layout
        float* h_proj      = (float*)(ws + 0);
        float* e           = (float*)(ws + 524288);
        float* context     = (float*)(ws + 786432);
        float* z           = (float*)(ws + 1310720);
        unsigned short* Wt = (unsigned short*)(ws + 3407872);

        k0_wt    <<<dim3(16, 16), dim3(32, 8), 0, stream>>>(Wi2h, Wt);
        k1_hproj <<<256, 256, 0, stream>>>(prev_h, Wh2h, bh2h, h_proj);
        k2_scores<<<1024, 256, 0, stream>>>(batch_H, Wt, h_proj, Wscore, e);
        k3_softmax<<<256, 256, 0, stream>>>(e, alpha);
        k4_context<<<dim3(2, 256), 256, 0, stream>>>(batch_H, alpha, context);
        k5_zgemm <<<dim3(16, 8), 256, 0, stream>>>(context, onehots, prev_h, Wk, Uk, z);
        k6_gates <<<512, 256, 0, stream>>>(z, bk, prev_c, out);
    }
}

// Round 3
// 177.097 us; speedup vs baseline: 2.0404x; 1.1299x over previous
//
#include <hip/hip_runtime.h>

typedef __bf16 bf16_t;
typedef bf16_t bf16x8 __attribute__((ext_vector_type(8)));
typedef unsigned short ushort8_t __attribute__((ext_vector_type(8)));
typedef unsigned short ushort4_t __attribute__((ext_vector_type(4)));
typedef float f32x4 __attribute__((ext_vector_type(4)));

__device__ __forceinline__ unsigned short f2bf(float f) {
    union { float f; unsigned int u; } v; v.f = f;
    unsigned int r = v.u + 0x7FFFu + ((v.u >> 16) & 1u);
    return (unsigned short)(r >> 16);
}
__device__ __forceinline__ float fast_tanh(float x) {
    float e2 = __expf(2.f * x);
    return 1.f - 2.f / (e2 + 1.f);
}
__device__ __forceinline__ float fast_sig(float x) {
    return 1.f / (1.f + __expf(-x));
}

// ---------------- K0: Wt[h][d] = bf16(W[d][h]) for a 512x512 fp32 matrix ----------------
__global__ void k0_wt(const float* __restrict__ W, unsigned short* __restrict__ Wt) {
    __shared__ float tile[32][33];
    int tx = threadIdx.x, ty = threadIdx.y;
    int bx = blockIdx.x, by = blockIdx.y;
#pragma unroll
    for (int j = 0; j < 4; ++j) {
        int r = by * 32 + ty + j * 8;
        int c = bx * 32 + tx;
        tile[ty + j * 8][tx] = W[r * 512 + c];
    }
    __syncthreads();
#pragma unroll
    for (int j = 0; j < 4; ++j) {
        int h = bx * 32 + ty + j * 8;
        int d = by * 32 + tx;
        Wt[h * 512 + d] = f2bf(tile[tx][ty + j * 8]);
    }
}

// ---------------- K1x: bf16 convert (float4 -> ushort4), n multiple of 1024 ----------------
__global__ void k1x_conv(const float* __restrict__ src, unsigned short* __restrict__ dst) {
    int i = blockIdx.x * 256 + threadIdx.x;
    float4 f = ((const float4*)src)[i];
    ushort4_t u;
    u[0] = f2bf(f.x); u[1] = f2bf(f.y); u[2] = f2bf(f.z); u[3] = f2bf(f.w);
    ((ushort4_t*)dst)[i] = u;
}

// ---------------- K1m: h_proj = prev_h @ Wh2h + bh2h via MFMA ----------------
// grid (8 h-tiles of 64, 8 m-tiles of 32), 256 threads, wave wc owns 16 h-cols.
__global__ void k1m_hproj(const unsigned short* __restrict__ ph_bf,   // [256][512] bf16
                          const unsigned short* __restrict__ Wht,     // [512 h][512 k] bf16
                          const float* __restrict__ bh2h,
                          float* __restrict__ h_proj) {
    int tid = threadIdx.x;
    int wave = tid >> 6, lane = tid & 63;
    int l15 = lane & 15, g = lane >> 4;
    int h0 = blockIdx.x * 64 + wave * 16;
    int m0 = blockIdx.y * 32;

    f32x4 acc[2];
    acc[0] = (f32x4){0.f, 0.f, 0.f, 0.f};
    acc[1] = (f32x4){0.f, 0.f, 0.f, 0.f};

    const unsigned short* abase = ph_bf + (size_t)(m0 + l15) * 512 + g * 8;
    const unsigned short* bbase = Wht + (size_t)(h0 + l15) * 512 + g * 8;
#pragma unroll
    for (int j = 0; j < 16; ++j) {
        bf16x8 bf = __builtin_bit_cast(bf16x8, *(const ushort8_t*)(bbase + j * 32));
        bf16x8 a0 = __builtin_bit_cast(bf16x8, *(const ushort8_t*)(abase + j * 32));
        bf16x8 a1 = __builtin_bit_cast(bf16x8, *(const ushort8_t*)(abase + 16 * 512 + j * 32));
        acc[0] = __builtin_amdgcn_mfma_f32_16x16x32_bf16(a0, bf, acc[0], 0, 0, 0);
        acc[1] = __builtin_amdgcn_mfma_f32_16x16x32_bf16(a1, bf, acc[1], 0, 0, 0);
    }
    int h = h0 + l15;
    float bias = bh2h[h];
#pragma unroll
    for (int mf = 0; mf < 2; ++mf)
#pragma unroll
        for (int r = 0; r < 4; ++r)
            h_proj[(size_t)(m0 + mf * 16 + g * 4 + r) * 512 + h] = acc[mf][r] + bias;
}

// ---------------- K2 v2: fused e = tanh(bH@Wi2h + h_proj) @ Wscore ----------------
// 512 blocks x 512 threads. Block tile: 128 rows x 512 cols, K=512.
// 8 waves = 2 (wr) x 4 (wc); wave tile 64 rows x 128 cols (mf=4, nf=8).
// BK=64 double-buffered LDS; B-frags register double-buffered; T14 stage split.
__launch_bounds__(512, 1)
__global__ void k2_scores(const float* __restrict__ batch_H,
                          const unsigned short* __restrict__ Wt,   // [512 h][512 d] bf16
                          const float* __restrict__ h_proj,
                          const float* __restrict__ Wscore,
                          float* __restrict__ e_out) {
    __shared__ __align__(16) unsigned short Alds[2 * 9216];  // 2 x 128 rows x 72 (64+8 pad)
    __shared__ float hp[512];
    __shared__ float wsc[512];
    __shared__ float e_red[4][128];

    int tid = threadIdx.x;
    int m0  = blockIdx.x * 128;
    int b   = m0 >> 8;

    hp[tid]  = h_proj[(size_t)b * 512 + tid];
    wsc[tid] = Wscore[tid];

    int wave = tid >> 6;
    int lane = tid & 63;
    int wr = wave >> 2;           // 0..1
    int wc = wave & 3;            // 0..3
    int l15 = lane & 15, g = lane >> 4;

    // staging geometry: thread covers row=tid>>2, 16 cols at (tid&3)*16 of the 64-wide slab
    int srow = tid >> 2;
    int scol = (tid & 3) << 4;
    const float* sbase = batch_H + (size_t)(m0 + srow) * 512 + scol;
    int sdst = srow * 72 + scol;

    f32x4 acc[4][8];
#pragma unroll
    for (int mf = 0; mf < 4; ++mf)
#pragma unroll
        for (int nf = 0; nf < 8; ++nf)
            acc[mf][nf] = (f32x4){0.f, 0.f, 0.f, 0.f};

    // prologue: stage slab 0 into buf 0
    {
        float4 a0 = *(const float4*)(sbase + 0);
        float4 a1 = *(const float4*)(sbase + 4);
        float4 a2 = *(const float4*)(sbase + 8);
        float4 a3 = *(const float4*)(sbase + 12);
        ushort8_t u0, u1;
        u0[0] = f2bf(a0.x); u0[1] = f2bf(a0.y); u0[2] = f2bf(a0.z); u0[3] = f2bf(a0.w);
        u0[4] = f2bf(a1.x); u0[5] = f2bf(a1.y); u0[6] = f2bf(a1.z); u0[7] = f2bf(a1.w);
        u1[0] = f2bf(a2.x); u1[1] = f2bf(a2.y); u1[2] = f2bf(a2.z); u1[3] = f2bf(a2.w);
        u1[4] = f2bf(a3.x); u1[5] = f2bf(a3.y); u1[6] = f2bf(a3.z); u1[7] = f2bf(a3.w);
        *(ushort8_t*)(&Alds[sdst])     = u0;
        *(ushort8_t*)(&Alds[sdst + 8]) = u1;
    }
    __syncthreads();

    const unsigned short* wbase = Wt + (size_t)(wc * 128 + l15) * 512 + g * 8;

    bf16x8 bcur[8], bnxt[8];
#pragma unroll
    for (int nf = 0; nf < 8; ++nf)
        bcur[nf] = __builtin_bit_cast(bf16x8, *(const ushort8_t*)(wbase + nf * 8192));

    float4 st0, st1, st2, st3;

#pragma unroll
    for (int j = 0; j < 16; ++j) {
        const int slab = j >> 1;
        const int buf  = slab & 1;
        const int kb   = j & 1;

        // (1) issue next slab's global loads early (T14 issue-early)
        if (kb == 0 && slab < 7) {
            const float* p = sbase + (slab + 1) * 64;
            st0 = *(const float4*)(p + 0);
            st1 = *(const float4*)(p + 4);
            st2 = *(const float4*)(p + 8);
            st3 = *(const float4*)(p + 12);
        }
        // (2) prefetch B fragments for next k-step
        if (j < 15) {
            int kk = (j + 1) * 32;
#pragma unroll
            for (int nf = 0; nf < 8; ++nf)
                bnxt[nf] = __builtin_bit_cast(bf16x8, *(const ushort8_t*)(wbase + nf * 8192 + kk));
        }
        // (3) A fragments from LDS
        bf16x8 afrag[4];
#pragma unroll
        for (int mf = 0; mf < 4; ++mf)
            afrag[mf] = __builtin_bit_cast(bf16x8,
                *(const ushort8_t*)(&Alds[buf * 9216 + (wr * 64 + mf * 16 + l15) * 72 + kb * 32 + g * 8]));
        // (4) MFMA cluster
#pragma unroll
        for (int nf = 0; nf < 8; ++nf)
#pragma unroll
            for (int mf = 0; mf < 4; ++mf)
                acc[mf][nf] = __builtin_amdgcn_mfma_f32_16x16x32_bf16(
                    afrag[mf], bcur[nf], acc[mf][nf], 0, 0, 0);
        // (5) write staged regs to the other buffer at slab end (T14 write-late)
        if (kb == 1 && slab < 7) {
            ushort8_t u0, u1;
            u0[0] = f2bf(st0.x); u0[1] = f2bf(st0.y); u0[2] = f2bf(st0.z); u0[3] = f2bf(st0.w);
            u0[4] = f2bf(st1.x); u0[5] = f2bf(st1.y); u0[6] = f2bf(st1.z); u0[7] = f2bf(st1.w);
            u1[0] = f2bf(st2.x); u1[1] = f2bf(st2.y); u1[2] = f2bf(st2.z); u1[3] = f2bf(st2.w);
            u1[4] = f2bf(st3.x); u1[5] = f2bf(st3.y); u1[6] = f2bf(st3.z); u1[7] = f2bf(st3.w);
            *(ushort8_t*)(&Alds[(buf ^ 1) * 9216 + sdst])     = u0;
            *(ushort8_t*)(&Alds[(buf ^ 1) * 9216 + sdst + 8]) = u1;
            __syncthreads();
        }
#pragma unroll
        for (int nf = 0; nf < 8; ++nf) bcur[nf] = bnxt[nf];
    }

    // epilogue: e_partial = sum_n wsc[n] * tanh(acc + hp[n])
    float s[4][4];
#pragma unroll
    for (int mf = 0; mf < 4; ++mf)
#pragma unroll
        for (int r = 0; r < 4; ++r) s[mf][r] = 0.f;

#pragma unroll
    for (int nf = 0; nf < 8; ++nf) {
        int n = wc * 128 + nf * 16 + l15;
        float hpv = hp[n], wv = wsc[n];
#pragma unroll
        for (int mf = 0; mf < 4; ++mf)
#pragma unroll
            for (int r = 0; r < 4; ++r)
                s[mf][r] += wv * fast_tanh(acc[mf][nf][r] + hpv);
    }
#pragma unroll
    for (int mf = 0; mf < 4; ++mf)
#pragma unroll
        for (int r = 0; r < 4; ++r) {
            float v = s[mf][r];
            v += __shfl_xor(v, 1);
            v += __shfl_xor(v, 2);
            v += __shfl_xor(v, 4);
            v += __shfl_xor(v, 8);
            s[mf][r] = v;
        }
    if (l15 == 0) {
#pragma unroll
        for (int mf = 0; mf < 4; ++mf)
#pragma unroll
            for (int r = 0; r < 4; ++r)
                e_red[wc][wr * 64 + mf * 16 + g * 4 + r] = s[mf][r];
    }
    __syncthreads();
    if (tid < 128) {
        e_out[m0 + tid] = e_red[0][tid] + e_red[1][tid] + e_red[2][tid] + e_red[3][tid];
    }
}

// ---------------- K3: softmax over T per b ----------------
__global__ void k3_softmax(const float* __restrict__ e, float* __restrict__ alpha_out) {
    __shared__ float red[4];
    int b = blockIdx.x, tid = threadIdx.x;
    float v = e[b * 256 + tid];
    float m = v;
#pragma unroll
    for (int off = 32; off; off >>= 1) m = fmaxf(m, __shfl_xor(m, off));
    if ((tid & 63) == 0) red[tid >> 6] = m;
    __syncthreads();
    m = fmaxf(fmaxf(red[0], red[1]), fmaxf(red[2], red[3]));
    float p = __expf(v - m);
    __syncthreads();
    float sum = p;
#pragma unroll
    for (int off = 32; off; off >>= 1) sum += __shfl_xor(sum, off);
    if ((tid & 63) == 0) red[tid >> 6] = sum;
    __syncthreads();
    sum = red[0] + red[1] + red[2] + red[3];
    alpha_out[b * 256 + tid] = p / sum;
}

// ---------------- K4: context[b,d] = sum_t alpha[b,t] * batch_H[b,t,d] ----------------
__global__ void k4_context(const float* __restrict__ batch_H, const float* __restrict__ alpha,
                           float* __restrict__ context) {
    __shared__ float al[256];
    int b = blockIdx.y, dc = blockIdx.x, tid = threadIdx.x;
    al[tid] = alpha[b * 256 + tid];
    __syncthreads();
    int d = dc * 256 + tid;
    const float* bh = batch_H + (size_t)b * 256 * 512 + d;
    float acc = 0.f;
#pragma unroll 4
    for (int t = 0; t < 256; ++t)
        acc += al[t] * bh[(size_t)t * 512];
    context[b * 512 + d] = acc;
}

// ---------------- K5t: Wzt[n][k] = bf16([Wk;Uk][k][n]), n<2048, k<1120 ----------------
__global__ void k5t_wzt(const float* __restrict__ Wk, const float* __restrict__ Uk,
                        unsigned short* __restrict__ Wzt) {
    __shared__ float tile[32][33];
    int tx = threadIdx.x, ty = threadIdx.y;
    int bx = blockIdx.x;   // k-tile, 0..34
    int by = blockIdx.y;   // n-tile, 0..63
#pragma unroll
    for (int j = 0; j < 4; ++j) {
        int k = bx * 32 + ty + j * 8;
        int c = by * 32 + tx;
        float v = (k < 608) ? Wk[(size_t)k * 2048 + c] : Uk[(size_t)(k - 608) * 2048 + c];
        tile[ty + j * 8][tx] = v;
    }
    __syncthreads();
#pragma unroll
    for (int j = 0; j < 4; ++j) {
        int n = by * 32 + ty + j * 8;
        int k = bx * 32 + tx;
        Wzt[(size_t)n * 1120 + k] = f2bf(tile[tx][ty + j * 8]);
    }
}

// ---------------- K5x: xb[b][k] = bf16([context;onehots;prev_h]) ----------------
__global__ void k5x_build(const float* __restrict__ context, const float* __restrict__ onehots,
                          const float* __restrict__ prev_h, unsigned short* __restrict__ xb) {
    int b = blockIdx.x, tid = threadIdx.x;
    for (int k = tid; k < 1120; k += 256) {
        float v;
        if (k < 512)      v = context[b * 512 + k];
        else if (k < 608) v = onehots[b * 96 + k - 512];
        else              v = prev_h[b * 512 + k - 608];
        xb[b * 1120 + k] = f2bf(v);
    }
}

// ---------------- K5m: fused z-GEMM + LSTM gates ----------------
__launch_bounds__(256)
__global__ void k5m_fused(const unsigned short* __restrict__ xb,   // [256][1120] bf16
                          const unsigned short* __restrict__ Wzt,  // [2048][1120] bf16
                          const float* __restrict__ bk,
                          const float* __restrict__ prev_c,
                          float* __restrict__ out) {
    __shared__ __align__(16) unsigned short Axs[32 * 232];

    int tid  = threadIdx.x;
    int wave = tid >> 6;
    int lane = tid & 63;
    int l15  = lane & 15;
    int g    = lane >> 4;
    int b0   = blockIdx.y * 32;
    int h0   = blockIdx.x * 64 + wave * 16;

    f32x4 acc[2][4];
#pragma unroll
    for (int mf = 0; mf < 2; ++mf)
#pragma unroll
        for (int gt = 0; gt < 4; ++gt)
            acc[mf][gt] = (f32x4){0.f, 0.f, 0.f, 0.f};

    const unsigned short* wbase = Wzt + (size_t)(h0 + l15) * 1120;

    for (int ks = 0; ks < 5; ++ks) {
        if (ks) __syncthreads();
        int kbase = ks * 224;
        for (int i = tid; i < 896; i += 256) {
            int row = i / 28;
            int c8  = (i % 28) * 8;
            *(ushort8_t*)(&Axs[row * 232 + c8]) =
                *(const ushort8_t*)(&xb[(size_t)(b0 + row) * 1120 + kbase + c8]);
        }
        __syncthreads();

        bf16x8 bcur[4], bnxt[4];
#pragma unroll
        for (int gt = 0; gt < 4; ++gt)
            bcur[gt] = __builtin_bit_cast(bf16x8,
                *(const ushort8_t*)(wbase + (size_t)gt * 512 * 1120 + kbase + g * 8));

#pragma unroll
        for (int kb = 0; kb < 7; ++kb) {
            if (kb < 6) {
                int kg = kbase + (kb + 1) * 32 + g * 8;
#pragma unroll
                for (int gt = 0; gt < 4; ++gt)
                    bnxt[gt] = __builtin_bit_cast(bf16x8,
                        *(const ushort8_t*)(wbase + (size_t)gt * 512 * 1120 + kg));
            }
            bf16x8 afrag[2];
#pragma unroll
            for (int mf = 0; mf < 2; ++mf)
                afrag[mf] = __builtin_bit_cast(bf16x8,
                    *(const ushort8_t*)(&Axs[(mf * 16 + l15) * 232 + kb * 32 + g * 8]));
#pragma unroll
            for (int gt = 0; gt < 4; ++gt)
#pragma unroll
                for (int mf = 0; mf < 2; ++mf)
                    acc[mf][gt] = __builtin_amdgcn_mfma_f32_16x16x32_bf16(
                        afrag[mf], bcur[gt], acc[mf][gt], 0, 0, 0);
#pragma unroll
            for (int gt = 0; gt < 4; ++gt) bcur[gt] = bnxt[gt];
        }
    }

    int h = h0 + l15;
    float bi = bk[h], bfv = bk[512 + h], bg = bk[1024 + h], bo = bk[1536 + h];
#pragma unroll
    for (int mf = 0; mf < 2; ++mf)
#pragma unroll
        for (int r = 0; r < 4; ++r) {
            int m = b0 + mf * 16 + g * 4 + r;
            float zi = acc[mf][0][r] + bi;
            float zf = acc[mf][1][r] + bfv;
            float zg = acc[mf][2][r] + bg;
            float zo = acc[mf][3][r] + bo;
            float c  = fast_sig(zf) * prev_c[m * 512 + h] + fast_sig(zi) * fast_tanh(zg);
            float hn = fast_sig(zo) * fast_tanh(c);
            out[m * 512 + h]          = hn;
            out[131072 + m * 512 + h] = c;
        }
}

extern "C" void kernel_launch(void* const* d_in, const int* in_sizes, int n_in,
                              void* d_out, int out_size, void* d_ws, size_t ws_size,
                              hipStream_t stream) {
    (void)in_sizes; (void)n_in; (void)out_size; (void)ws_size;
    const float* prev_h  = (const float*)d_in[0];
    const float* prev_c  = (const float*)d_in[1];
    const float* batch_H = (const float*)d_in[2];
    const float* onehots = (const float*)d_in[3];
    const float* Wi2h    = (const float*)d_in[4];
    const float* Wh2h    = (const float*)d_in[5];
    const float* bh2h    = (const float*)d_in[6];
    const float* Wscore  = (const float*)d_in[7];
    const float* Wk      = (const float*)d_in[8];
    const float* Uk      = (const float*)d_in[9];
    const float* bk      = (const float*)d_in[10];
    float* out = (float*)d_out;
    float* alpha = out + 262144;

    char* ws = (char*)d_ws;
    // Phase A (k0..k3): offsets 0 .. 2097152 hold Wt/Wht/ph_bf/h_proj/e (all dead after k3)
    unsigned short* Wt     = (unsigned short*)(ws + 0);        // 524288 B
    unsigned short* Wht    = (unsigned short*)(ws + 524288);   // 524288 B
    unsigned short* ph_bf  = (unsigned short*)(ws + 1048576);  // 262144 B
    float*          h_proj = (float*)(ws + 1310720);           // 524288 B
    float*          e      = (float*)(ws + 1835008);           // 262144 B
    // Phase B (k5t..k5m): Wzt overwrites [0, 4587520) after phase A is dead
    unsigned short* Wzt    = (unsigned short*)(ws + 0);        // 4587520 B
    unsigned short* xb     = (unsigned short*)(ws + 4784128);  // 573440 B, ends 5357568
    float*          context= (float*)(ws + 5373952);           // 524288 B, ends 5898240

    k0_wt     <<<dim3(16, 16), dim3(32, 8), 0, stream>>>(Wi2h, Wt);
    k0_wt     <<<dim3(16, 16), dim3(32, 8), 0, stream>>>(Wh2h, Wht);
    k1x_conv  <<<128, 256, 0, stream>>>(prev_h, ph_bf);
    k1m_hproj <<<dim3(8, 8), 256, 0, stream>>>(ph_bf, Wht, bh2h, h_proj);
    k2_scores <<<512, 512, 0, stream>>>(batch_H, Wt, h_proj, Wscore, e);
    k3_softmax<<<256, 256, 0, stream>>>(e, alpha);
    k4_context<<<dim3(2, 256), 256, 0, stream>>>(batch_H, alpha, context);
    k5t_wzt   <<<dim3(35, 64), dim3(32, 8), 0, stream>>>(Wk, Uk, Wzt);
    k5x_build <<<256, 256, 0, stream>>>(context, onehots, prev_h, xb);
    k5m_fused <<<dim3(8, 8), 256, 0, stream>>>(xb, Wzt, bk, prev_c, out);
}

// Round 4
// 145.499 us; speedup vs baseline: 2.4836x; 1.2172x over previous
//
#include <hip/hip_runtime.h>

typedef __bf16 bf16_t;
typedef bf16_t bf16x8 __attribute__((ext_vector_type(8)));
typedef unsigned short ushort8_t __attribute__((ext_vector_type(8)));
typedef unsigned short ushort4_t __attribute__((ext_vector_type(4)));
typedef float f32x4 __attribute__((ext_vector_type(4)));

__device__ __forceinline__ unsigned short f2bf(float f) {
    union { float f; unsigned int u; } v; v.f = f;
    unsigned int r = v.u + 0x7FFFu + ((v.u >> 16) & 1u);
    return (unsigned short)(r >> 16);
}
__device__ __forceinline__ float fast_tanh(float x) {
    float e2 = __expf(2.f * x);
    return 1.f - 2.f / (e2 + 1.f);
}
__device__ __forceinline__ float fast_sig(float x) {
    return 1.f / (1.f + __expf(-x));
}

// ---------------- K0: two 512x512 transpose+bf16 converts in one launch ----------------
__global__ void k0_wt2(const float* __restrict__ Wi2h, const float* __restrict__ Wh2h,
                       unsigned short* __restrict__ Wt, unsigned short* __restrict__ Wht) {
    __shared__ float tile[32][33];
    const float* W = blockIdx.z ? Wh2h : Wi2h;
    unsigned short* O = blockIdx.z ? Wht : Wt;
    int tx = threadIdx.x, ty = threadIdx.y;
    int bx = blockIdx.x, by = blockIdx.y;
#pragma unroll
    for (int j = 0; j < 4; ++j) {
        int r = by * 32 + ty + j * 8;
        int c = bx * 32 + tx;
        tile[ty + j * 8][tx] = W[r * 512 + c];
    }
    __syncthreads();
#pragma unroll
    for (int j = 0; j < 4; ++j) {
        int h = bx * 32 + ty + j * 8;
        int d = by * 32 + tx;
        O[h * 512 + d] = f2bf(tile[tx][ty + j * 8]);
    }
}

// ---------------- K1x: bf16 convert (float4 -> ushort4) ----------------
__global__ void k1x_conv(const float* __restrict__ src, unsigned short* __restrict__ dst) {
    int i = blockIdx.x * 256 + threadIdx.x;
    float4 f = ((const float4*)src)[i];
    ushort4_t u;
    u[0] = f2bf(f.x); u[1] = f2bf(f.y); u[2] = f2bf(f.z); u[3] = f2bf(f.w);
    ((ushort4_t*)dst)[i] = u;
}

// ---------------- K1m: h_proj = prev_h @ Wh2h + bh2h via MFMA ----------------
__global__ void k1m_hproj(const unsigned short* __restrict__ ph_bf,   // [256][512] bf16
                          const unsigned short* __restrict__ Wht,     // [512 h][512 k] bf16
                          const float* __restrict__ bh2h,
                          float* __restrict__ h_proj) {
    int tid = threadIdx.x;
    int wave = tid >> 6, lane = tid & 63;
    int l15 = lane & 15, g = lane >> 4;
    int h0 = blockIdx.x * 64 + wave * 16;
    int m0 = blockIdx.y * 32;

    f32x4 acc[2];
    acc[0] = (f32x4){0.f, 0.f, 0.f, 0.f};
    acc[1] = (f32x4){0.f, 0.f, 0.f, 0.f};

    const unsigned short* abase = ph_bf + (size_t)(m0 + l15) * 512 + g * 8;
    const unsigned short* bbase = Wht + (size_t)(h0 + l15) * 512 + g * 8;
#pragma unroll
    for (int j = 0; j < 16; ++j) {
        bf16x8 bf = __builtin_bit_cast(bf16x8, *(const ushort8_t*)(bbase + j * 32));
        bf16x8 a0 = __builtin_bit_cast(bf16x8, *(const ushort8_t*)(abase + j * 32));
        bf16x8 a1 = __builtin_bit_cast(bf16x8, *(const ushort8_t*)(abase + 16 * 512 + j * 32));
        acc[0] = __builtin_amdgcn_mfma_f32_16x16x32_bf16(a0, bf, acc[0], 0, 0, 0);
        acc[1] = __builtin_amdgcn_mfma_f32_16x16x32_bf16(a1, bf, acc[1], 0, 0, 0);
    }
    int h = h0 + l15;
    float bias = bh2h[h];
#pragma unroll
    for (int mf = 0; mf < 2; ++mf)
#pragma unroll
        for (int r = 0; r < 4; ++r)
            h_proj[(size_t)(m0 + mf * 16 + g * 4 + r) * 512 + h] = acc[mf][r] + bias;
}

// ---------------- K2 v3: m97-structure partial-e GEMM ----------------
// Grid 2048 = 512 m-tiles x 4 n-tiles (XCD-swizzled). 256 threads = 4 waves (2x2).
// Block tile 128(m) x 128(n), K=512, BK=64; wave tile 64x64 (acc 4x4 f32x4 = 64 regs).
// B via global_load_lds w16 with pre-swizzled source; A reg-staged fp32->bf16, swizzled ds_write.
// Swizzle: slot s at row r holds k-chunk s ^ (r&7)  (16B chunks, involution).
__launch_bounds__(256, 2)
__global__ void k2_scores(const float* __restrict__ batch_H,
                          const unsigned short* __restrict__ Wt,   // [512 h][512 d] bf16
                          const float* __restrict__ h_proj,
                          const float* __restrict__ Wscore,
                          float* __restrict__ e_part) {            // [4][65536]
    __shared__ __align__(16) unsigned short Alds[8192];  // 128 rows x 64 k (8 chunks)
    __shared__ __align__(16) unsigned short Blds[8192];  // 128 rows x 64 k
    __shared__ float hp_s[128];
    __shared__ float wsc_s[128];
    __shared__ float e_red[4][64];

    int tid = threadIdx.x;
    // bijective XCD swizzle: consecutive wg within an XCD chunk -> n fastest
    int wg = (blockIdx.x & 7) * 256 + (blockIdx.x >> 3);
    int mt = wg >> 2, nt = wg & 3;
    int m0 = mt * 128, n0 = nt * 128;
    int b  = m0 >> 8;

    if (tid < 128) hp_s[tid] = h_proj[(size_t)b * 512 + n0 + tid];
    else           wsc_s[tid - 128] = Wscore[n0 + tid - 128];

    int wave = tid >> 6;
    int lane = tid & 63;
    int wr = wave >> 1;          // 0..1 row-half
    int wc = wave & 1;           // 0..1 col-half
    int l15 = lane & 15, g = lane >> 4;
    int bchunk = ((lane & 7) ^ (lane >> 3)) << 3;   // pre-swizzled k-elem offset for B source
    int brow_l = lane >> 3;                          // 0..7 row within 8-row group

    f32x4 acc[4][4];
#pragma unroll
    for (int mf = 0; mf < 4; ++mf)
#pragma unroll
        for (int nf = 0; nf < 4; ++nf)
            acc[mf][nf] = (f32x4){0.f, 0.f, 0.f, 0.f};

    for (int ks = 0; ks < 8; ++ks) {
        __syncthreads();
        int kbase = ks * 64;
        // ---- B: 4 global_load_lds (1 KB each) per wave, source pre-swizzled ----
#pragma unroll
        for (int i = 0; i < 4; ++i) {
            int q = wave * 4 + i;                    // 8-row group 0..15
            int row = q * 8 + brow_l;
            const unsigned short* gsrc = Wt + (size_t)(n0 + row) * 512 + kbase + bchunk;
            __builtin_amdgcn_global_load_lds(
                (const __attribute__((address_space(1))) void*)gsrc,
                (__attribute__((address_space(3))) void*)&Blds[q * 512], 16, 0, 0);
        }
        // ---- A: coalesced fp32 loads ----
        float4 av[8];
#pragma unroll
        for (int j = 0; j < 8; ++j) {
            int idx = j * 256 + tid;                 // float4 index in 128x64 slab
            int r = idx >> 4, c4 = idx & 15;
            av[j] = *(const float4*)(batch_H + (size_t)(m0 + r) * 512 + kbase + c4 * 4);
        }
        // ---- convert + swizzled ds_write_b64 ----
#pragma unroll
        for (int j = 0; j < 8; ++j) {
            int idx = j * 256 + tid;
            int r = idx >> 4, c4 = idx & 15;
            ushort4_t u;
            u[0] = f2bf(av[j].x); u[1] = f2bf(av[j].y);
            u[2] = f2bf(av[j].z); u[3] = f2bf(av[j].w);
            int boff = r * 128 + ((((c4 >> 1) ^ (r & 7)) << 4) | ((c4 & 1) << 3));
            *(ushort4_t*)((char*)Alds + boff) = u;
        }
        __syncthreads();   // drains gload_lds (vmcnt) + ds_writes
        // ---- compute: 2 k-steps x (4 af + 4 bf reads, 16 MFMA) ----
#pragma unroll
        for (int kk = 0; kk < 2; ++kk) {
            bf16x8 af[4], bf[4];
#pragma unroll
            for (int mf = 0; mf < 4; ++mf) {
                int row = wr * 64 + mf * 16 + l15;
                int boff = row * 128 + ((((kk * 4 + g) ^ (l15 & 7))) << 4);
                af[mf] = __builtin_bit_cast(bf16x8, *(const ushort8_t*)((char*)Alds + boff));
            }
#pragma unroll
            for (int nf = 0; nf < 4; ++nf) {
                int row = wc * 64 + nf * 16 + l15;
                int boff = row * 128 + ((((kk * 4 + g) ^ (l15 & 7))) << 4);
                bf[nf] = __builtin_bit_cast(bf16x8, *(const ushort8_t*)((char*)Blds + boff));
            }
#pragma unroll
            for (int nf = 0; nf < 4; ++nf)
#pragma unroll
                for (int mf = 0; mf < 4; ++mf)
                    acc[mf][nf] = __builtin_amdgcn_mfma_f32_16x16x32_bf16(
                        af[mf], bf[nf], acc[mf][nf], 0, 0, 0);
        }
    }

    // ---- epilogue: partial e over this block's 128 n-cols ----
    float s[4][4];
#pragma unroll
    for (int mf = 0; mf < 4; ++mf)
#pragma unroll
        for (int r = 0; r < 4; ++r) s[mf][r] = 0.f;

#pragma unroll
    for (int nf = 0; nf < 4; ++nf) {
        int nl = wc * 64 + nf * 16 + l15;
        float hpv = hp_s[nl], wv = wsc_s[nl];
#pragma unroll
        for (int mf = 0; mf < 4; ++mf)
#pragma unroll
            for (int r = 0; r < 4; ++r)
                s[mf][r] += wv * fast_tanh(acc[mf][nf][r] + hpv);
    }
#pragma unroll
    for (int mf = 0; mf < 4; ++mf)
#pragma unroll
        for (int r = 0; r < 4; ++r) {
            float v = s[mf][r];
            v += __shfl_xor(v, 1);
            v += __shfl_xor(v, 2);
            v += __shfl_xor(v, 4);
            v += __shfl_xor(v, 8);
            s[mf][r] = v;
        }
    if (l15 == 0) {
#pragma unroll
        for (int mf = 0; mf < 4; ++mf)
#pragma unroll
            for (int r = 0; r < 4; ++r)
                e_red[wave][mf * 16 + g * 4 + r] = s[mf][r];
    }
    __syncthreads();
    if (tid < 128) {
        int wrr = tid >> 6, i64 = tid & 63;
        float v = e_red[wrr * 2 + 0][i64] + e_red[wrr * 2 + 1][i64];
        e_part[(size_t)nt * 65536 + m0 + tid] = v;
    }
}

// ---------------- K3: sum 4 e-partials + softmax over T per b ----------------
__global__ void k3_softmax(const float* __restrict__ e_part, float* __restrict__ alpha_out) {
    __shared__ float red[4];
    int b = blockIdx.x, tid = threadIdx.x;
    int m = b * 256 + tid;
    float v = e_part[m] + e_part[65536 + m] + e_part[131072 + m] + e_part[196608 + m];
    float mx = v;
#pragma unroll
    for (int off = 32; off; off >>= 1) mx = fmaxf(mx, __shfl_xor(mx, off));
    if ((tid & 63) == 0) red[tid >> 6] = mx;
    __syncthreads();
    mx = fmaxf(fmaxf(red[0], red[1]), fmaxf(red[2], red[3]));
    float p = __expf(v - mx);
    __syncthreads();
    float sum = p;
#pragma unroll
    for (int off = 32; off; off >>= 1) sum += __shfl_xor(sum, off);
    if ((tid & 63) == 0) red[tid >> 6] = sum;
    __syncthreads();
    sum = red[0] + red[1] + red[2] + red[3];
    alpha_out[b * 256 + tid] = p / sum;
}

// ---------------- K4: context[b,d] = sum_t alpha[b,t] * batch_H[b,t,d] ----------------
__global__ void k4_context(const float* __restrict__ batch_H, const float* __restrict__ alpha,
                           float* __restrict__ context) {
    __shared__ float al[256];
    int b = blockIdx.y, dc = blockIdx.x, tid = threadIdx.x;
    al[tid] = alpha[b * 256 + tid];
    __syncthreads();
    int d = dc * 256 + tid;
    const float* bh = batch_H + (size_t)b * 256 * 512 + d;
    float acc = 0.f;
#pragma unroll 4
    for (int t = 0; t < 256; ++t)
        acc += al[t] * bh[(size_t)t * 512];
    context[b * 512 + d] = acc;
}

// ---------------- K5t: Wzt[n][k] = bf16([Wk;Uk][k][n]), n<2048, k<1120 ----------------
__global__ void k5t_wzt(const float* __restrict__ Wk, const float* __restrict__ Uk,
                        unsigned short* __restrict__ Wzt) {
    __shared__ float tile[32][33];
    int tx = threadIdx.x, ty = threadIdx.y;
    int bx = blockIdx.x;   // k-tile, 0..34
    int by = blockIdx.y;   // n-tile, 0..63
#pragma unroll
    for (int j = 0; j < 4; ++j) {
        int k = bx * 32 + ty + j * 8;
        int c = by * 32 + tx;
        float v = (k < 608) ? Wk[(size_t)k * 2048 + c] : Uk[(size_t)(k - 608) * 2048 + c];
        tile[ty + j * 8][tx] = v;
    }
    __syncthreads();
#pragma unroll
    for (int j = 0; j < 4; ++j) {
        int n = by * 32 + ty + j * 8;
        int k = bx * 32 + tx;
        Wzt[(size_t)n * 1120 + k] = f2bf(tile[tx][ty + j * 8]);
    }
}

// ---------------- K5x: xb[b][k] = bf16([context;onehots;prev_h]) ----------------
__global__ void k5x_build(const float* __restrict__ context, const float* __restrict__ onehots,
                          const float* __restrict__ prev_h, unsigned short* __restrict__ xb) {
    int b = blockIdx.x, tid = threadIdx.x;
    for (int k = tid; k < 1120; k += 256) {
        float v;
        if (k < 512)      v = context[b * 512 + k];
        else if (k < 608) v = onehots[b * 96 + k - 512];
        else              v = prev_h[b * 512 + k - 608];
        xb[b * 1120 + k] = f2bf(v);
    }
}

// ---------------- K5m: fused z-GEMM + LSTM gates ----------------
__launch_bounds__(256)
__global__ void k5m_fused(const unsigned short* __restrict__ xb,   // [256][1120] bf16
                          const unsigned short* __restrict__ Wzt,  // [2048][1120] bf16
                          const float* __restrict__ bk,
                          const float* __restrict__ prev_c,
                          float* __restrict__ out) {
    __shared__ __align__(16) unsigned short Axs[32 * 232];

    int tid  = threadIdx.x;
    int wave = tid >> 6;
    int lane = tid & 63;
    int l15  = lane & 15;
    int g    = lane >> 4;
    int b0   = blockIdx.y * 32;
    int h0   = blockIdx.x * 64 + wave * 16;

    f32x4 acc[2][4];
#pragma unroll
    for (int mf = 0; mf < 2; ++mf)
#pragma unroll
        for (int gt = 0; gt < 4; ++gt)
            acc[mf][gt] = (f32x4){0.f, 0.f, 0.f, 0.f};

    const unsigned short* wbase = Wzt + (size_t)(h0 + l15) * 1120;

    for (int ks = 0; ks < 5; ++ks) {
        if (ks) __syncthreads();
        int kbase = ks * 224;
        for (int i = tid; i < 896; i += 256) {
            int row = i / 28;
            int c8  = (i % 28) * 8;
            *(ushort8_t*)(&Axs[row * 232 + c8]) =
                *(const ushort8_t*)(&xb[(size_t)(b0 + row) * 1120 + kbase + c8]);
        }
        __syncthreads();

        bf16x8 bcur[4], bnxt[4];
#pragma unroll
        for (int gt = 0; gt < 4; ++gt)
            bcur[gt] = __builtin_bit_cast(bf16x8,
                *(const ushort8_t*)(wbase + (size_t)gt * 512 * 1120 + kbase + g * 8));

#pragma unroll
        for (int kb = 0; kb < 7; ++kb) {
            if (kb < 6) {
                int kg = kbase + (kb + 1) * 32 + g * 8;
#pragma unroll
                for (int gt = 0; gt < 4; ++gt)
                    bnxt[gt] = __builtin_bit_cast(bf16x8,
                        *(const ushort8_t*)(wbase + (size_t)gt * 512 * 1120 + kg));
            }
            bf16x8 afrag[2];
#pragma unroll
            for (int mf = 0; mf < 2; ++mf)
                afrag[mf] = __builtin_bit_cast(bf16x8,
                    *(const ushort8_t*)(&Axs[(mf * 16 + l15) * 232 + kb * 32 + g * 8]));
#pragma unroll
            for (int gt = 0; gt < 4; ++gt)
#pragma unroll
                for (int mf = 0; mf < 2; ++mf)
                    acc[mf][gt] = __builtin_amdgcn_mfma_f32_16x16x32_bf16(
                        afrag[mf], bcur[gt], acc[mf][gt], 0, 0, 0);
#pragma unroll
            for (int gt = 0; gt < 4; ++gt) bcur[gt] = bnxt[gt];
        }
    }

    int h = h0 + l15;
    float bi = bk[h], bfv = bk[512 + h], bg = bk[1024 + h], bo = bk[1536 + h];
#pragma unroll
    for (int mf = 0; mf < 2; ++mf)
#pragma unroll
        for (int r = 0; r < 4; ++r) {
            int m = b0 + mf * 16 + g * 4 + r;
            float zi = acc[mf][0][r] + bi;
            float zf = acc[mf][1][r] + bfv;
            float zg = acc[mf][2][r] + bg;
            float zo = acc[mf][3][r] + bo;
            float c  = fast_sig(zf) * prev_c[m * 512 + h] + fast_sig(zi) * fast_tanh(zg);
            float hn = fast_sig(zo) * fast_tanh(c);
            out[m * 512 + h]          = hn;
            out[131072 + m * 512 + h] = c;
        }
}

extern "C" void kernel_launch(void* const* d_in, const int* in_sizes, int n_in,
                              void* d_out, int out_size, void* d_ws, size_t ws_size,
                              hipStream_t stream) {
    (void)in_sizes; (void)n_in; (void)out_size; (void)ws_size;
    const float* prev_h  = (const float*)d_in[0];
    const float* prev_c  = (const float*)d_in[1];
    const float* batch_H = (const float*)d_in[2];
    const float* onehots = (const float*)d_in[3];
    const float* Wi2h    = (const float*)d_in[4];
    const float* Wh2h    = (const float*)d_in[5];
    const float* bh2h    = (const float*)d_in[6];
    const float* Wscore  = (const float*)d_in[7];
    const float* Wk      = (const float*)d_in[8];
    const float* Uk      = (const float*)d_in[9];
    const float* bk      = (const float*)d_in[10];
    float* out = (float*)d_out;
    float* alpha = out + 262144;

    char* ws = (char*)d_ws;
    // Phase A (dead by k5t): [0, 2883584)
    unsigned short* Wt     = (unsigned short*)(ws + 0);        // 524288
    unsigned short* Wht    = (unsigned short*)(ws + 524288);   // 524288
    unsigned short* ph_bf  = (unsigned short*)(ws + 1048576);  // 262144
    float*          h_proj = (float*)(ws + 1310720);           // 524288
    float*          e_part = (float*)(ws + 1835008);           // 1048576, ends 2883584
    // Phase B: Wzt overwrites [0, 4587520) after Phase A dead
    unsigned short* Wzt    = (unsigned short*)(ws + 0);        // 4587520
    unsigned short* xb     = (unsigned short*)(ws + 4587520);  // 573440, ends 5160960
    float*          context= (float*)(ws + 5160960);           // 524288, ends 5685248

    k0_wt2    <<<dim3(16, 16, 2), dim3(32, 8), 0, stream>>>(Wi2h, Wh2h, Wt, Wht);
    k1x_conv  <<<128, 256, 0, stream>>>(prev_h, ph_bf);
    k1m_hproj <<<dim3(8, 8), 256, 0, stream>>>(ph_bf, Wht, bh2h, h_proj);
    k2_scores <<<2048, 256, 0, stream>>>(batch_H, Wt, h_proj, Wscore, e_part);
    k3_softmax<<<256, 256, 0, stream>>>(e_part, alpha);
    k4_context<<<dim3(2, 256), 256, 0, stream>>>(batch_H, alpha, context);
    k5t_wzt   <<<dim3(35, 64), dim3(32, 8), 0, stream>>>(Wk, Uk, Wzt);
    k5x_build <<<256, 256, 0, stream>>>(context, onehots, prev_h, xb);
    k5m_fused <<<dim3(8, 8), 256, 0, stream>>>(xb, Wzt, bk, prev_c, out);
}